// Round 1
// baseline (598.554 us; speedup 1.0000x reference)
//
#include <hip/hip_runtime.h>
#include <cstdint>

// Problem constants (from reference)
#define M_ROWS 8192
#define HIDDEN 4096
#define GROUP  128        // fp8 group size == HEAD_DIM
#define NGRP   32         // HIDDEN / GROUP
#define FP8MAX 448.0f
#define EPSV   1e-6f

using float4_t = __attribute__((ext_vector_type(4))) float;

// ---------------------------------------------------------------------------
// async global -> LDS, 16 bytes per lane. LDS dest is wave-uniform base +
// lane*16 (global_load_lds constraint); global source may be per-lane.
// ---------------------------------------------------------------------------
__device__ __forceinline__ void async_ld16(const void* g, void* l) {
    __builtin_amdgcn_global_load_lds(
        (const __attribute__((address_space(1))) void*)g,
        (__attribute__((address_space(3))) void*)l, 16, 0, 0);
}

// ---------------------------------------------------------------------------
// Kernel 1: relu(x), relu(z), per-head RMSNorm * norm_weight * silu(z),
// per-(row,head) fp8 e4m3 quantization.  One wave (64 lanes) per head;
// each lane owns 2 consecutive elements.
// a      : [M][HIDDEN] fp8 bytes
// a_sc   : [M][NGRP]   fp32 scales
// ---------------------------------------------------------------------------
__global__ __launch_bounds__(256)
void act_quant_kernel(const float* __restrict__ x, const float* __restrict__ z,
                      const float* __restrict__ nw,
                      uint8_t* __restrict__ a, float* __restrict__ a_sc) {
    const int tid  = threadIdx.x;
    const int lane = tid & 63;
    const int wv   = tid >> 6;
    const long gh  = (long)blockIdx.x * 4 + wv;   // global head index = row*32 + h
    const long row = gh >> 5;
    const int  h   = (int)(gh & 31);
    const long base = row * HIDDEN + (long)h * GROUP + lane * 2;

    float2 xv = *(const float2*)(x + base);
    float2 zv = *(const float2*)(z + base);
    float x0 = fmaxf(xv.x, 0.f), x1 = fmaxf(xv.y, 0.f);   // relu
    float z0 = fmaxf(zv.x, 0.f), z1 = fmaxf(zv.y, 0.f);   // relu

    // mean of squares over the 128-elem head (wave butterfly reduce)
    float ss = x0 * x0 + x1 * x1;
    #pragma unroll
    for (int o = 32; o > 0; o >>= 1) ss += __shfl_xor(ss, o, 64);
    const float rstd = 1.0f / sqrtf(ss * (1.0f / 128.0f) + EPSV);

    const float w0 = nw[lane * 2], w1 = nw[lane * 2 + 1];
    // silu(z) = z * sigmoid(z); z >= 0 after relu so exp(-z) is safe
    const float s0 = z0 / (1.f + expf(-z0));
    const float s1 = z1 / (1.f + expf(-z1));
    const float g0 = x0 * rstd * w0 * s0;
    const float g1 = x1 * rstd * w1 * s1;

    // group absmax (wave reduce)
    float am = fmaxf(fabsf(g0), fabsf(g1));
    #pragma unroll
    for (int o = 32; o > 0; o >>= 1) am = fmaxf(am, __shfl_xor(am, o, 64));
    const float scale = fmaxf(am, 1e-12f) / FP8MAX;

    // quantize (exact division to match reference), HW RNE fp8 pack
    const int packed = __builtin_amdgcn_cvt_pk_fp8_f32(g0 / scale, g1 / scale, 0, false);
    *(uint16_t*)(a + base) = (uint16_t)(packed & 0xffff);
    if (lane == 0) a_sc[row * NGRP + h] = scale;
}

// ---------------------------------------------------------------------------
// Kernel 2: per-(128,128)-block fp8 quantization of w.
// Block (jb,kb) handles w[jb*128 : +128][kb*128 : +128].
// wq   : [HIDDEN][HIDDEN] fp8 bytes (same layout as w: [j][k])
// w_sc : [NGRP][NGRP] fp32, index [jb][kb]
// ---------------------------------------------------------------------------
__global__ __launch_bounds__(256)
void w_quant_kernel(const float* __restrict__ w, uint8_t* __restrict__ wq,
                    float* __restrict__ w_sc) {
    const int jb = blockIdx.x, kb = blockIdx.y;
    const int tid  = threadIdx.x;
    const int lane = tid & 63;
    const int wv   = tid >> 6;
    const int r     = tid >> 1;          // 0..127 row within block
    const int cbase = (tid & 1) * 64;    // half-row per thread (64 elems)
    const float* src = w + (long)(jb * 128 + r) * HIDDEN + kb * 128 + cbase;

    float am = 0.f;
    #pragma unroll
    for (int i = 0; i < 16; ++i) {
        float4_t v = *(const float4_t*)(src + i * 4);
        am = fmaxf(am, fmaxf(fmaxf(fabsf(v[0]), fabsf(v[1])),
                             fmaxf(fabsf(v[2]), fabsf(v[3]))));
    }
    #pragma unroll
    for (int o = 32; o > 0; o >>= 1) am = fmaxf(am, __shfl_xor(am, o, 64));

    __shared__ float red[4];
    if (lane == 0) red[wv] = am;
    __syncthreads();
    am = fmaxf(fmaxf(red[0], red[1]), fmaxf(red[2], red[3]));
    const float scale = fmaxf(am, 1e-12f) / FP8MAX;
    if (tid == 0) w_sc[jb * NGRP + kb] = scale;

    uint8_t* dst = wq + (long)(jb * 128 + r) * HIDDEN + kb * 128 + cbase;
    #pragma unroll
    for (int i = 0; i < 16; ++i) {
        float4_t v = *(const float4_t*)(src + i * 4);   // L1/L2-hot re-read
        int p = __builtin_amdgcn_cvt_pk_fp8_f32(v[0] / scale, v[1] / scale, 0, false);
        p     = __builtin_amdgcn_cvt_pk_fp8_f32(v[2] / scale, v[3] / scale, p, true);
        *(uint32_t*)(dst + i * 4) = (uint32_t)p;
    }
}

// ---------------------------------------------------------------------------
// Kernel 3: blockwise-scaled fp8 GEMM.  C[n][j] = sum over 128-K groups of
// a_sc[n,kg]*w_sc[jb,kg] * (fp8 dot over the group).
// 128x128 C tile / block, 4 waves in 2x2, each wave 4x4 tiles of 16x16.
// BK = 128 = one scale group per staging iteration.
// LDS chunk placement XOR-swizzled: slot cs of row r holds global 16B-chunk
// cs^(r&7), so stride-128B fragment reads hit the 4-access/bank structural
// optimum instead of a 16-way conflict.
// ---------------------------------------------------------------------------
__global__ __launch_bounds__(256, 2)
void gemm_fp8_scaled(const uint8_t* __restrict__ A, const float* __restrict__ As,
                     const uint8_t* __restrict__ B, const float* __restrict__ Bs,
                     float* __restrict__ C) {
    constexpr int K = HIDDEN;
    __shared__ uint8_t lA[128 * 128];
    __shared__ uint8_t lB[128 * 128];
    __shared__ float   lAs[NGRP * 128];   // [kg][row] (transposed for b128 reads)

    const int tid  = threadIdx.x;
    const int lane = tid & 63;
    const int wv   = tid >> 6;
    const long row0 = (long)blockIdx.x * 128;
    const long col0 = (long)blockIdx.y * 128;

    // stage the block's a-scales, transposed: lAs[kg*128 + r] = As[(row0+r)*32+kg]
    for (int i = tid; i < NGRP * 128; i += 256) {
        int r = i & 127, g = i >> 7;
        lAs[g * 128 + r] = As[(row0 + r) * NGRP + g];
    }

    const int m    = lane & 15;     // MFMA A-row / D-col index
    const int quad = lane >> 4;
    const int wm = (wv & 1) * 64;   // wave's 64x64 quadrant
    const int wn = (wv >> 1) * 64;

    const int srow = tid >> 3;      // staging: 32 rows per pass
    const int slot = tid & 7;       // staging: LDS chunk slot within row

    float4_t acc[4][4] = {};

    for (int kg = 0; kg < NGRP; ++kg) {
        // ---- stage A and B 128x128-byte tiles (swizzled chunk choice) ----
        #pragma unroll
        for (int p = 0; p < 4; ++p) {
            int r = p * 32 + srow;
            int c = slot ^ (r & 7);
            async_ld16(A + (row0 + r) * K + kg * 128 + c * 16,
                       &lA[p * 4096 + tid * 16]);
        }
        #pragma unroll
        for (int p = 0; p < 4; ++p) {
            int r = p * 32 + srow;
            int c = slot ^ (r & 7);
            async_ld16(B + (col0 + r) * K + kg * 128 + c * 16,
                       &lB[p * 4096 + tid * 16]);
        }
        __syncthreads();   // drains vmcnt (global_load_lds) + covers lAs on kg==0

        // ---- fp8 MFMA over the group into a partial accumulator ----
        float4_t part[4][4] = {};
        #pragma unroll
        for (int ks = 0; ks < 4; ++ks) {
            const int c16 = ks * 2 + (quad >> 1);
            const int hof = (quad & 1) * 8;
            long af[4], bf[4];
            #pragma unroll
            for (int t = 0; t < 4; ++t) {
                int r = wm + t * 16 + m;
                af[t] = *(const long*)&lA[r * 128 + ((c16 ^ (r & 7)) * 16) + hof];
            }
            #pragma unroll
            for (int t = 0; t < 4; ++t) {
                int r = wn + t * 16 + m;
                bf[t] = *(const long*)&lB[r * 128 + ((c16 ^ (r & 7)) * 16) + hof];
            }
            #pragma unroll
            for (int mt = 0; mt < 4; ++mt)
                #pragma unroll
                for (int nt = 0; nt < 4; ++nt)
                    part[mt][nt] = __builtin_amdgcn_mfma_f32_16x16x32_fp8_fp8(
                        af[mt], bf[nt], part[mt][nt], 0, 0, 0);
        }
        __syncthreads();   // LDS tiles free for next iteration

        // ---- fold group scales: acc += (a_sc[row]*w_sc) * part ----
        const float wsc = Bs[blockIdx.y * NGRP + kg];   // uniform per block
        #pragma unroll
        for (int mt = 0; mt < 4; ++mt) {
            // D rows for this lane: wm + mt*16 + quad*4 + reg, reg=0..3 (consecutive)
            float4_t as4 = *(const float4_t*)&lAs[kg * 128 + wm + mt * 16 + quad * 4];
            float s0 = as4[0] * wsc, s1 = as4[1] * wsc;
            float s2 = as4[2] * wsc, s3 = as4[3] * wsc;
            #pragma unroll
            for (int nt = 0; nt < 4; ++nt) {
                acc[mt][nt][0] += s0 * part[mt][nt][0];
                acc[mt][nt][1] += s1 * part[mt][nt][1];
                acc[mt][nt][2] += s2 * part[mt][nt][2];
                acc[mt][nt][3] += s3 * part[mt][nt][3];
            }
        }
    }

    // ---- epilogue: C/D layout col=lane&15, row=quad*4+reg ----
    #pragma unroll
    for (int mt = 0; mt < 4; ++mt)
        #pragma unroll
        for (int nt = 0; nt < 4; ++nt) {
            const long r  = row0 + wm + mt * 16 + quad * 4;
            const long cc = col0 + wn + nt * 16 + m;
            #pragma unroll
            for (int g = 0; g < 4; ++g)
                C[(r + g) * HIDDEN + cc] = acc[mt][nt][g];
        }
}

// ---------------------------------------------------------------------------
extern "C" void kernel_launch(void* const* d_in, const int* in_sizes, int n_in,
                              void* d_out, int out_size, void* d_ws, size_t ws_size,
                              hipStream_t stream) {
    const float* x  = (const float*)d_in[0];
    const float* z  = (const float*)d_in[1];
    const float* nw = (const float*)d_in[2];
    const float* w  = (const float*)d_in[3];
    float* out = (float*)d_out;

    // workspace layout (~51.4 MB)
    uint8_t* ws8   = (uint8_t*)d_ws;
    uint8_t* a_fp8 = ws8;                                   // 8192*4096   = 32 MiB
    uint8_t* w_fp8 = ws8 + (size_t)M_ROWS * HIDDEN;         // 4096*4096   = 16 MiB
    float*   a_sc  = (float*)(w_fp8 + (size_t)HIDDEN * HIDDEN);      // 1 MiB
    float*   w_sc  = a_sc + (size_t)M_ROWS * NGRP;                   // 4 KiB

    act_quant_kernel<<<M_ROWS * NGRP / 4, 256, 0, stream>>>(x, z, nw, a_fp8, a_sc);
    w_quant_kernel<<<dim3(NGRP, NGRP), 256, 0, stream>>>(w, w_fp8, w_sc);
    gemm_fp8_scaled<<<dim3(M_ROWS / 128, HIDDEN / 128), 256, 0, stream>>>(
        a_fp8, a_sc, w_fp8, w_sc, out);
}